// Round 18
// baseline (1126.507 us; speedup 1.0000x reference)
//
#include <hip/hip_runtime.h>

#define IN_F 4096
#define OUT_F 11008
#define NGROUPS 32
#define M_TOTAL 8192
#define BM 256
#define BN 256
#define BK 32
#define NPH 128  // phases; phase p covers K [p*32, p*32+32)

typedef _Float16 half_t;  // storage only; payload bf16 bits
typedef unsigned short ushort_t;
typedef __attribute__((ext_vector_type(8))) short short8;
typedef __attribute__((ext_vector_type(4))) float f32x4;
typedef __attribute__((ext_vector_type(4))) int i32x4;
typedef __attribute__((ext_vector_type(4))) unsigned short us4;

typedef __attribute__((address_space(1))) const void gvoid_t;
typedef __attribute__((address_space(3))) void lvoid_t;

__device__ __forceinline__ unsigned short f32_to_bf16_rne(float f) {
  unsigned int u = __builtin_bit_cast(unsigned int, f);
  u += 0x7FFFu + ((u >> 16) & 1u);
  return (unsigned short)(u >> 16);
}

// ---------------- prepass 1: x fp32 -> bf16 (RNE) ----------------
__global__ void convert_x_k(const float* __restrict__ x, ushort_t* __restrict__ xh) {
  const int n4 = M_TOTAL * IN_F / 4;
  int stride = gridDim.x * blockDim.x;
  for (int i = blockIdx.x * blockDim.x + threadIdx.x; i < n4; i += stride) {
    f32x4 v = __builtin_nontemporal_load((const f32x4*)x + i);
    us4 h;
    h[0] = f32_to_bf16_rne(v[0]);
    h[1] = f32_to_bf16_rne(v[1]);
    h[2] = f32_to_bf16_rne(v[2]);
    h[3] = f32_to_bf16_rne(v[3]);
    ((us4*)xh)[i] = h;
  }
}

// ---------------- prepass 2: W (int32-materialized int8) * group scale -> bf16 ----------
__global__ void dequant_w_k(const int* __restrict__ wq,
                            const float* __restrict__ scales,
                            ushort_t* __restrict__ wh) {
  int row = blockIdx.x;
  int t = threadIdx.x;
  size_t base = (size_t)row * IN_F + (size_t)t * 8;
  float s = scales[row * NGROUPS + (t >> 4)];
  i32x4 q0 = __builtin_nontemporal_load((const i32x4*)(wq + base));
  i32x4 q1 = __builtin_nontemporal_load((const i32x4*)(wq + base) + 1);
  us4 h0, h1;
#pragma unroll
  for (int j = 0; j < 4; ++j) h0[j] = f32_to_bf16_rne((float)q0[j] * s);
#pragma unroll
  for (int j = 0; j < 4; ++j) h1[j] = f32_to_bf16_rne((float)q1[j] * s);
  *(us4*)(wh + base) = h0;
  *(us4*)(wh + base + 4) = h1;
}

// ---- 256x256 GEMM: A via LDS (2 slots, swizzled), B DIRECT global->reg ----
// Phase p: rd a0,a1 from Alds[(p>>1)&1][p&1]; load B(p+1) regs (4 dwordx4, L2-hit;
// B frag = 16 contiguous bytes along K => per-lane address, no LDS needed);
// stage A unit (T+1, p&1) -> slot^1; split LGKM; 32 MFMA; VMCNT(6); BAR.
// Removes 32/96 LDS reads + 16/32 KB LDS stage-writes per r14 phase-pair.
// Ledger: stage target's last reader drained at its lgkm before bar(p-2) ✓;
// VMCNT(6) at end of p leaves exactly p's {4 B + 2 stage} ops => stage(p-1)
// retired before bar => readable at p+1 ✓; b(p) retired by compiler-inserted
// vmcnt before its MFMA use. Tail fences 4, 0. K-order identical => absmax 1.0.

#define BAR() __builtin_amdgcn_s_barrier()
#define SB0() __builtin_amdgcn_sched_barrier(0)
#define PRIO1() __builtin_amdgcn_s_setprio(1)
#define PRIO0() __builtin_amdgcn_s_setprio(0)
#define VMCNT(N) asm volatile("s_waitcnt vmcnt(" #N ")" ::: "memory")
#define LGKM(N) asm volatile("s_waitcnt lgkmcnt(" #N ")" ::: "memory")
#define GLD(G, D) __builtin_amdgcn_global_load_lds((gvoid_t*)(G), (lvoid_t*)(D), 16, 0, 0)

#define ALDS(S, KH) (smem + (S) * 32768 + (KH) * 16384)

#define LOADB(BSET, KOFF)                                                      \
  _Pragma("unroll") for (int n_ = 0; n_ < 4; ++n_)                             \
      BSET[n_] = *(const short8*)(pB + (size_t)n_ * 16 * IN_F + (KOFF));

#define STAGEA(KOFF, S, KH)                                                    \
  do {                                                                         \
    const half_t* g_ = pAsrc + (KOFF);                                         \
    char* d_ = ALDS(S, KH) + tid * 16;                                         \
    GLD(g_, d_);                                                               \
    GLD(g_ + 128 * IN_F, d_ + 8192);                                           \
  } while (0)

#define MFMA_H(ASET, BSET, MH)                                                 \
  _Pragma("unroll") for (int i_ = 0; i_ < 4; ++i_)                             \
      _Pragma("unroll") for (int j_ = 0; j_ < 4; ++j_)                         \
          acc[(MH)*4 + i_][j_] = __builtin_amdgcn_mfma_f32_16x16x32_bf16(      \
              ASET[i_], BSET[j_], acc[(MH)*4 + i_][j_], 0, 0, 0);

// Phase. BLD: 1 = load BNXT at KOFFB. STG: 1 = stage at KOFFS. FEN: vmcnt at end.
#define PHASE(S, KH, BCUR, BNXT, BLD, KOFFB, STG, KOFFS, FEN)                  \
  do {                                                                         \
    const char* Ab_ = ALDS(S, KH);                                             \
    _Pragma("unroll") for (int m_ = 0; m_ < 4; ++m_)                           \
        a0[m_] = *(const short8*)(Ab_ + aoff + m_ * 1024);                     \
    SB0();                                                                     \
    _Pragma("unroll") for (int m_ = 0; m_ < 4; ++m_)                           \
        a1[m_] = *(const short8*)(Ab_ + aoff + 4096 + m_ * 1024);              \
    if (BLD) { LOADB(BNXT, KOFFB); }                                           \
    if (STG) { STAGEA(KOFFS, (S) ^ 1, KH); }                                   \
    LGKM(4); SB0(); PRIO1();                                                   \
    MFMA_H(a0, BCUR, 0);                                                       \
    LGKM(0); SB0();                                                            \
    MFMA_H(a1, BCUR, 1);                                                       \
    PRIO0();                                                                   \
    if ((FEN) == 6) VMCNT(6);                                                  \
    if ((FEN) == 4) VMCNT(4);                                                  \
    if ((FEN) == 0) VMCNT(0);                                                  \
    BAR(); SB0();                                                              \
  } while (0)

__global__ __launch_bounds__(512, 1) void gemm_k(const half_t* __restrict__ A,
                                                 const half_t* __restrict__ B,
                                                 const float* __restrict__ bias,
                                                 float* __restrict__ C) {
  __shared__ __align__(16) char smem[65536];  // A only: 2 slots x [kh][256x32] bf16

  const int tid = threadIdx.x;
  const int lane = tid & 63;
  const int wv = tid >> 6;
  const int wm = wv >> 2;  // 2 wave-rows (128 rows)
  const int wn = wv & 3;   // 4 wave-cols (64 cols)

  // Band-rasterized, XCD-aware map (nwg = 1376 = 8*172, bijective)
  const int nwg = gridDim.x;
  const int perx = nwg >> 3;
  const int L = ((int)blockIdx.x & 7) * perx + ((int)blockIdx.x >> 3);
  const int band = L >> 7;
  const int rr_ = L & 127;
  const int bn0 = band << 2;
  const int cols = (43 - bn0) < 4 ? (43 - bn0) : 4;
  const int bm = rr_ / cols;
  const int bn = bn0 + rr_ % cols;
  const int row0 = bm * BM;
  const int col0 = bn * BN;

  // A staging source (pre-swizzled; involution c ^= (row&6)<<3)
  const int c16 = (tid & 3) * 16;
  const int srow = tid >> 2;
  const int clog = c16 ^ ((srow & 6) << 3);
  const int kidx = clog >> 1;
  const half_t* pAsrc = A + (size_t)(row0 + srow) * IN_F + kidx;

  // fragment addressing
  const int r16 = lane & 15;
  const int kg = lane >> 4;
  const int aoff = (wm * 128 + r16) * 64 + ((kg * 16) ^ ((r16 & 6) << 3));
  // B direct: lane reads B[col][k...k+8), col = col0+wn*64+nf*16+r16, k = p*32+kg*8
  const half_t* pB = B + (size_t)(col0 + wn * 64 + r16) * IN_F + kg * 8;

  f32x4 acc[8][4];
#pragma unroll
  for (int m = 0; m < 8; ++m)
#pragma unroll
    for (int n = 0; n < 4; ++n) acc[m][n] = (f32x4){0.f, 0.f, 0.f, 0.f};

  short8 a0[4], a1[4], bA[4], bB[4];

  // prologue: stage tile0 (kh0,kh1) -> slot0; load B(0) -> bA.
  // vmcnt(4): the 4 stage gloads retired (only B(0)'s 4 reg-loads outstanding).
  STAGEA(0, 0, 0);
  STAGEA(32, 0, 1);
  LOADB(bA, 0);
  VMCNT(4);
  BAR();
  SB0();

  for (int u = 0; u < 63; ++u) {  // phases 0..125
    const int p0 = 2 * u;
    const int s = u & 1;
    // phase p0 (even, cur=bA): B(p0+1)->bB; stage (T+1,kh0) src (p0+2)*32
    PHASE(s, 0, bA, bB, 1, (p0 + 1) * 32, 1, (p0 + 2) * 32, 6);
    // phase p0+1 (odd, cur=bB): B(p0+2)->bA; stage (T+1,kh1) src (p0+3)*32
    PHASE(s, 1, bB, bA, 1, (p0 + 2) * 32, 1, (p0 + 3) * 32, 6);
  }
  // p=126 (tile63, slot1, kh0, cur=bA): load B(127)->bB; no stage; fence 4
  PHASE(1, 0, bA, bB, 1, 127 * 32, 0, 0, 4);
  // p=127 (slot1, kh1, cur=bB): nothing outstanding needed; fence 0
  PHASE(1, 1, bB, bA, 0, 0, 0, 0, 0);

  // epilogue: fp16 rounding + fp16 bias add (reference numerics), NT fp32 store
  const int kg4 = kg * 4;
#pragma unroll
  for (int nf = 0; nf < 4; ++nf) {
    int col = col0 + wn * 64 + nf * 16 + r16;
    _Float16 bh = (_Float16)bias[col];
#pragma unroll
    for (int mf = 0; mf < 8; ++mf) {
      int rb = row0 + wm * 128 + mf * 16 + kg4;
#pragma unroll
      for (int r = 0; r < 4; ++r) {
        _Float16 v = (_Float16)acc[mf][nf][r] + bh;
        __builtin_nontemporal_store((float)v, &C[(size_t)(rb + r) * OUT_F + col]);
      }
    }
  }
}

// ---------------- emergency fallback (ws too small) ----------------
__global__ void naive_k(const float* __restrict__ x, const int* __restrict__ wq,
                        const float* __restrict__ scales, const float* __restrict__ bias,
                        float* __restrict__ out) {
  long idx = (long)blockIdx.x * blockDim.x + threadIdx.x;
  if (idx >= (long)M_TOTAL * OUT_F) return;
  int m = (int)(idx / OUT_F);
  int n = (int)(idx % OUT_F);
  float acc = 0.f;
  for (int g = 0; g < NGROUPS; ++g) {
    float s = scales[n * NGROUPS + g];
    for (int k = g * 128; k < (g + 1) * 128; ++k) {
      _Float16 xv = (_Float16)x[(size_t)m * IN_F + k];
      _Float16 wv = (_Float16)((float)wq[(size_t)n * IN_F + k] * s);
      acc += (float)xv * (float)wv;
    }
  }
  _Float16 r = (_Float16)acc + (_Float16)bias[n];
  out[idx] = (float)r;
}

extern "C" void kernel_launch(void* const* d_in, const int* in_sizes, int n_in,
                              void* d_out, int out_size, void* d_ws, size_t ws_size,
                              hipStream_t stream) {
  const float* x = (const float*)d_in[0];
  const int* wq = (const int*)d_in[1];
  const float* scales = (const float*)d_in[2];
  const float* bias = (const float*)d_in[3];
  float* out = (float*)d_out;

  const size_t xh_bytes = (size_t)M_TOTAL * IN_F * 2;
  const size_t wh_bytes = (size_t)OUT_F * IN_F * 2;

  if (ws_size >= xh_bytes + wh_bytes) {
    ushort_t* xh = (ushort_t*)d_ws;
    ushort_t* wh = (ushort_t*)((char*)d_ws + xh_bytes);
    convert_x_k<<<2048, 256, 0, stream>>>(x, xh);
    dequant_w_k<<<OUT_F, 512, 0, stream>>>(wq, scales, wh);
    gemm_k<<<(M_TOTAL / BM) * (OUT_F / BN), 512, 0, stream>>>(
        (const half_t*)xh, (const half_t*)wh, bias, out);
  } else {
    long total = (long)M_TOTAL * OUT_F;
    naive_k<<<(int)((total + 255) / 256), 256, 0, stream>>>(x, wq, scales, bias, out);
  }
}

// Round 19
// 899.607 us; speedup vs baseline: 1.2522x; 1.2522x over previous
//
#include <hip/hip_runtime.h>

#define IN_F 4096
#define OUT_F 11008
#define NGROUPS 32
#define M_TOTAL 8192
#define BM 256
#define BN 256
#define BK 64

typedef _Float16 half_t;  // storage only; payload bf16 bits
typedef unsigned short ushort_t;
typedef __attribute__((ext_vector_type(8))) short short8;
typedef __attribute__((ext_vector_type(4))) float f32x4;
typedef __attribute__((ext_vector_type(4))) int i32x4;
typedef __attribute__((ext_vector_type(4))) unsigned short us4;

typedef __attribute__((address_space(1))) const void gvoid_t;
typedef __attribute__((address_space(3))) void lvoid_t;

__device__ __forceinline__ unsigned short f32_to_bf16_rne(float f) {
  unsigned int u = __builtin_bit_cast(unsigned int, f);
  u += 0x7FFFu + ((u >> 16) & 1u);
  return (unsigned short)(u >> 16);
}

// ---------------- prepass 1: x fp32 -> bf16 (RNE) ----------------
__global__ void convert_x_k(const float* __restrict__ x, ushort_t* __restrict__ xh) {
  const int n4 = M_TOTAL * IN_F / 4;
  int stride = gridDim.x * blockDim.x;
  for (int i = blockIdx.x * blockDim.x + threadIdx.x; i < n4; i += stride) {
    f32x4 v = __builtin_nontemporal_load((const f32x4*)x + i);
    us4 h;
    h[0] = f32_to_bf16_rne(v[0]);
    h[1] = f32_to_bf16_rne(v[1]);
    h[2] = f32_to_bf16_rne(v[2]);
    h[3] = f32_to_bf16_rne(v[3]);
    ((us4*)xh)[i] = h;
  }
}

// ---------------- prepass 2: W (int32-materialized int8) * group scale -> bf16 ----------
__global__ void dequant_w_k(const int* __restrict__ wq,
                            const float* __restrict__ scales,
                            ushort_t* __restrict__ wh) {
  int row = blockIdx.x;
  int t = threadIdx.x;
  size_t base = (size_t)row * IN_F + (size_t)t * 8;
  float s = scales[row * NGROUPS + (t >> 4)];
  i32x4 q0 = __builtin_nontemporal_load((const i32x4*)(wq + base));
  i32x4 q1 = __builtin_nontemporal_load((const i32x4*)(wq + base) + 1);
  us4 h0, h1;
#pragma unroll
  for (int j = 0; j < 4; ++j) h0[j] = f32_to_bf16_rne((float)q0[j] * s);
#pragma unroll
  for (int j = 0; j < 4; ++j) h1[j] = f32_to_bf16_rne((float)q1[j] * s);
  *(us4*)(wh + base) = h0;
  *(us4*)(wh + base + 4) = h1;
}

// --- 256x256 GEMM, 4 waves x (128x128)/wave: LDS reads/MFMA 0.375 -> 0.25 ---
// 256 threads, 1 wave/SIMD (acc 8x8 f32x4 = 256 VGPR; ~344 total, fits 512 budget).
// Rationale: serial-sum model (validated r7-r16) => wall = MFMA + LDS + sync; only
// traffic cuts moved the needle. Bigger wave tile cuts LDS b128 reads/CU/phase
// 96 -> 64 (frag reuse x2 on B). MFMA/SIMD invariant.
// LDS [slot][op][kh][256x32] bf16 (r13 layout, 0-conflict geometry), swizzle
// c ^= (row&6)<<3 both sides. Stage: 4 GLD rounds per (op,kh) unit (256 thr x 16 B
// x 4 = 16 KB); 2 units = 8 GLD per phase.
// Stage map (iter u, t1=2u+1, n0=2u+2, n1=2u+3):
//   MP1(s0,kh0): {Ak1,Bk1}(t1)->s1   MP2(s0,kh1): {Ak0,Bk0}(n0)->s0
//   MP3(s1,kh0): {Ak1,Bk1}(n0)->s0   MP4(s1,kh1): {Ak0,Bk0}(n1)->s1
// VMCNT(16)/phase (8 loads/phase; leaves 2 newest phases in flight; retires the
// 2-unit group read next phase — audited incl. prologue/peel). Peel fences 16,8,0.
// Split lgkm: issue b[0..7],a[0..3] | a[4..7]; LGKM(4) -> b+a0..3; LGKM(0) -> rest.

#define BAR() __builtin_amdgcn_s_barrier()
#define SB0() __builtin_amdgcn_sched_barrier(0)
#define PRIO1() __builtin_amdgcn_s_setprio(1)
#define PRIO0() __builtin_amdgcn_s_setprio(0)
#define VMCNT(N) asm volatile("s_waitcnt vmcnt(" #N ")" ::: "memory")
#define LGKM(N) asm volatile("s_waitcnt lgkmcnt(" #N ")" ::: "memory")
#define GLD(G, D) __builtin_amdgcn_global_load_lds((gvoid_t*)(G), (lvoid_t*)(D), 16, 0, 0)

#define STAGE(OP, KH, KT, S)                                                   \
  do {                                                                         \
    const half_t* g_ = ((OP) ? pBsrc : pAsrc) + (KT) * 64 + (KH) * 32;         \
    char* d_ = (char*)&lds[S][OP][KH][0] + tid * 16;                           \
    GLD(g_, d_);                                                               \
    GLD(g_ + 64 * IN_F, d_ + 4096);                                            \
    GLD(g_ + 128 * IN_F, d_ + 8192);                                           \
    GLD(g_ + 192 * IN_F, d_ + 12288);                                          \
  } while (0)

#define MFMA_HALF(M0)                                                          \
  _Pragma("unroll") for (int m_ = 0; m_ < 4; ++m_)                             \
      _Pragma("unroll") for (int n_ = 0; n_ < 8; ++n_)                         \
          acc[(M0) + m_][n_] = __builtin_amdgcn_mfma_f32_16x16x32_bf16(        \
              a[(M0) + m_], b[n_], acc[(M0) + m_][n_], 0, 0, 0);

// Merged phase. FEN: 16/8/0 = vmcnt(N), -1 = none. STG: 1 = do the 2 stages.
#define MPH(SL, KH, STG, S1OP, S1KT, S1SL, S1KH, S2OP, S2KT, S2SL, S2KH, FEN)  \
  do {                                                                         \
    const char* Ab_ = (const char*)&lds[SL][0][KH][0];                         \
    const char* Bb_ = (const char*)&lds[SL][1][KH][0];                         \
    _Pragma("unroll") for (int n_ = 0; n_ < 8; ++n_)                           \
        b[n_] = *(const short8*)(Bb_ + boff + n_ * 1024);                      \
    _Pragma("unroll") for (int m_ = 0; m_ < 4; ++m_)                           \
        a[m_] = *(const short8*)(Ab_ + aoff + m_ * 1024);                      \
    SB0();                                                                     \
    _Pragma("unroll") for (int m_ = 4; m_ < 8; ++m_)                           \
        a[m_] = *(const short8*)(Ab_ + aoff + m_ * 1024);                      \
    if (STG) {                                                                 \
      STAGE(S1OP, S1KH, S1KT, S1SL);                                           \
      STAGE(S2OP, S2KH, S2KT, S2SL);                                           \
    }                                                                          \
    LGKM(4); SB0(); PRIO1();                                                   \
    MFMA_HALF(0);                                                              \
    LGKM(0); SB0();                                                            \
    MFMA_HALF(4);                                                              \
    PRIO0();                                                                   \
    if ((FEN) == 16) VMCNT(16);                                                \
    if ((FEN) == 8) VMCNT(8);                                                  \
    if ((FEN) == 0) VMCNT(0);                                                  \
    BAR(); SB0();                                                              \
  } while (0)

__global__ __launch_bounds__(256, 1) void gemm_k(const half_t* __restrict__ A,
                                                 const half_t* __restrict__ B,
                                                 const float* __restrict__ bias,
                                                 float* __restrict__ C) {
  __shared__ __align__(16) half_t lds[2][2][2][8192];  // 128 KiB (r13 layout)

  const int tid = threadIdx.x;
  const int lane = tid & 63;
  const int wv = tid >> 6;   // 4 waves
  const int wr = wv >> 1;    // 2 wave-rows (128 rows each)
  const int wc = wv & 1;     // 2 wave-cols (128 cols each)

  // Band-rasterized, XCD-aware map (nwg = 1376 = 8*172, bijective)
  const int nwg = gridDim.x;
  const int perx = nwg >> 3;
  const int L = ((int)blockIdx.x & 7) * perx + ((int)blockIdx.x >> 3);
  const int band = L >> 7;
  const int rr_ = L & 127;
  const int bn0 = band << 2;
  const int cols = (43 - bn0) < 4 ? (43 - bn0) : 4;
  const int bm = rr_ / cols;
  const int bn = bn0 + rr_ % cols;
  const int row0 = bm * BM;
  const int col0 = bn * BN;

  // staging source (pre-swizzled; involution c ^= (row&6)<<3); 256 thr cover
  // rows 0..63 per round, rounds add 64 rows (64&6==0 preserves the swizzle bits)
  const int c16 = (tid & 3) * 16;
  const int srow = tid >> 2;  // 0..63
  const int clog = c16 ^ ((srow & 6) << 3);
  const int kidx = clog >> 1;
  const half_t* pAsrc = A + (size_t)(row0 + srow) * IN_F + kidx;
  const half_t* pBsrc = B + (size_t)(col0 + srow) * IN_F + kidx;

  // fragment read offsets (swizzled); frag stride 16 rows * 64 B = 1024
  const int r16 = lane & 15;
  const int kg = lane >> 4;
  const int aoff = (wr * 128 + r16) * 64 + ((kg * 16) ^ ((r16 & 6) << 3));
  const int boff = (wc * 128 + r16) * 64 + ((kg * 16) ^ ((r16 & 6) << 3));

  f32x4 acc[8][8];
#pragma unroll
  for (int m = 0; m < 8; ++m)
#pragma unroll
    for (int n = 0; n < 8; ++n) acc[m][n] = (f32x4){0.f, 0.f, 0.f, 0.f};

  short8 a[8], b[8];

  // prologue: tile0 all 4 units + tile1 {Ak0,Bk0} (24 GLDs); VMCNT(8): tile0 landed
  STAGE(0, 0, 0, 0);
  STAGE(1, 0, 0, 0);
  STAGE(0, 1, 0, 0);
  STAGE(1, 1, 0, 0);
  STAGE(0, 0, 1, 1);
  STAGE(1, 0, 1, 1);
  VMCNT(8);
  BAR();
  SB0();

  for (int u = 0; u < 31; ++u) {
    const int t1 = 2 * u + 1, n0 = 2 * u + 2, n1 = 2 * u + 3;
    MPH(0, 0, 1, 0, t1, 1, 1, 1, t1, 1, 1, 16);  // MP1: s0kh0; stage {Ak1,Bk1}(t1)->s1
    MPH(0, 1, 1, 0, n0, 0, 0, 1, n0, 0, 0, 16);  // MP2: s0kh1; stage {Ak0,Bk0}(n0)->s0
    MPH(1, 0, 1, 0, n0, 0, 1, 1, n0, 0, 1, 16);  // MP3: s1kh0; stage {Ak1,Bk1}(n0)->s0
    MPH(1, 1, 1, 0, n1, 1, 0, 1, n1, 1, 0, 16);  // MP4: s1kh1; stage {Ak0,Bk0}(n1)->s1
  }
  {  // peeled iter 31 (t0=62, t1=63): MP1 stages {Ak1,Bk1}(63)->s1; drain 16/8/0
    MPH(0, 0, 1, 0, 63, 1, 1, 1, 63, 1, 1, 16);
    MPH(0, 1, 0, 0, 0, 0, 0, 0, 0, 0, 0, 8);   // retires {Ak0,Bk0}(63) for MP3
    MPH(1, 0, 0, 0, 0, 0, 0, 0, 0, 0, 0, 0);   // retires {Ak1,Bk1}(63) for MP4
    MPH(1, 1, 0, 0, 0, 0, 0, 0, 0, 0, 0, -1);
  }

  // epilogue: fp16 rounding + fp16 bias add (reference numerics), NT fp32 store
  const int kg4 = kg * 4;
#pragma unroll
  for (int nf = 0; nf < 8; ++nf) {
    int col = col0 + wc * 128 + nf * 16 + r16;
    _Float16 bh = (_Float16)bias[col];
#pragma unroll
    for (int mf = 0; mf < 8; ++mf) {
      int rb = row0 + wr * 128 + mf * 16 + kg4;
#pragma unroll
      for (int r = 0; r < 4; ++r) {
        _Float16 v = (_Float16)acc[mf][nf][r] + bh;
        __builtin_nontemporal_store((float)v, &C[(size_t)(rb + r) * OUT_F + col]);
      }
    }
  }
}

// ---------------- emergency fallback (ws too small) ----------------
__global__ void naive_k(const float* __restrict__ x, const int* __restrict__ wq,
                        const float* __restrict__ scales, const float* __restrict__ bias,
                        float* __restrict__ out) {
  long idx = (long)blockIdx.x * blockDim.x + threadIdx.x;
  if (idx >= (long)M_TOTAL * OUT_F) return;
  int m = (int)(idx / OUT_F);
  int n = (int)(idx % OUT_F);
  float acc = 0.f;
  for (int g = 0; g < NGROUPS; ++g) {
    float s = scales[n * NGROUPS + g];
    for (int k = g * 128; k < (g + 1) * 128; ++k) {
      _Float16 xv = (_Float16)x[(size_t)m * IN_F + k];
      _Float16 wv = (_Float16)((float)wq[(size_t)n * IN_F + k] * s);
      acc += (float)xv * (float)wv;
    }
  }
  _Float16 r = (_Float16)acc + (_Float16)bias[n];
  out[idx] = (float)r;
}

extern "C" void kernel_launch(void* const* d_in, const int* in_sizes, int n_in,
                              void* d_out, int out_size, void* d_ws, size_t ws_size,
                              hipStream_t stream) {
  const float* x = (const float*)d_in[0];
  const int* wq = (const int*)d_in[1];
  const float* scales = (const float*)d_in[2];
  const float* bias = (const float*)d_in[3];
  float* out = (float*)d_out;

  const size_t xh_bytes = (size_t)M_TOTAL * IN_F * 2;
  const size_t wh_bytes = (size_t)OUT_F * IN_F * 2;

  if (ws_size >= xh_bytes + wh_bytes) {
    ushort_t* xh = (ushort_t*)d_ws;
    ushort_t* wh = (ushort_t*)((char*)d_ws + xh_bytes);
    convert_x_k<<<2048, 256, 0, stream>>>(x, xh);
    dequant_w_k<<<OUT_F, 512, 0, stream>>>(wq, scales, wh);
    gemm_k<<<(M_TOTAL / BM) * (OUT_F / BN), 256, 0, stream>>>(
        (const half_t*)xh, (const half_t*)wh, bias, out);
  } else {
    long total = (long)M_TOTAL * OUT_F;
    naive_k<<<(int)((total + 255) / 256), 256, 0, stream>>>(x, wq, scales, bias, out);
  }
}

// Round 20
// 713.799 us; speedup vs baseline: 1.5782x; 1.2603x over previous
//
#include <hip/hip_runtime.h>

#define IN_F 4096
#define OUT_F 11008
#define NGROUPS 32
#define M_TOTAL 8192
#define BM 256
#define BN 256
#define BK 64
#define NKT (IN_F / BK)  // 64 K-tiles; 32 iters x (2 K-tiles / 4 merged phases)

typedef _Float16 half_t;  // LDS element size only (2 B); payload is bf16 bits
typedef unsigned short ushort_t;
typedef __attribute__((ext_vector_type(8))) short short8;   // bf16x8 frag (4 VGPR)
typedef __attribute__((ext_vector_type(4))) float f32x4;
typedef __attribute__((ext_vector_type(4))) int i32x4;
typedef __attribute__((ext_vector_type(4))) unsigned short us4;

typedef __attribute__((address_space(1))) const void gvoid_t;
typedef __attribute__((address_space(3))) void lvoid_t;

__device__ __forceinline__ unsigned short f32_to_bf16_rne(float f) {
  unsigned int u = __builtin_bit_cast(unsigned int, f);
  u += 0x7FFFu + ((u >> 16) & 1u);
  return (unsigned short)(u >> 16);
}

// ---------------- prepass 1: x fp32 -> bf16 (RNE) ----------------
__global__ void convert_x_k(const float* __restrict__ x, ushort_t* __restrict__ xh) {
  const int n4 = M_TOTAL * IN_F / 4;
  int stride = gridDim.x * blockDim.x;
  for (int i = blockIdx.x * blockDim.x + threadIdx.x; i < n4; i += stride) {
    f32x4 v = __builtin_nontemporal_load((const f32x4*)x + i);
    us4 h;
    h[0] = f32_to_bf16_rne(v[0]);
    h[1] = f32_to_bf16_rne(v[1]);
    h[2] = f32_to_bf16_rne(v[2]);
    h[3] = f32_to_bf16_rne(v[3]);
    ((us4*)xh)[i] = h;
  }
}

// ---------------- prepass 2: W (int32-materialized int8) * group scale -> bf16 ----------
__global__ void dequant_w_k(const int* __restrict__ wq,
                            const float* __restrict__ scales,
                            ushort_t* __restrict__ wh) {
  int row = blockIdx.x;
  int t = threadIdx.x;  // 512 threads, 8 weights each
  size_t base = (size_t)row * IN_F + (size_t)t * 8;
  float s = scales[row * NGROUPS + (t >> 4)];
  i32x4 q0 = __builtin_nontemporal_load((const i32x4*)(wq + base));
  i32x4 q1 = __builtin_nontemporal_load((const i32x4*)(wq + base) + 1);
  us4 h0, h1;
#pragma unroll
  for (int j = 0; j < 4; ++j) h0[j] = f32_to_bf16_rne((float)q0[j] * s);
#pragma unroll
  for (int j = 0; j < 4; ++j) h1[j] = f32_to_bf16_rne((float)q1[j] * s);
  *(us4*)(wh + base) = h0;
  *(us4*)(wh + base + 4) = h1;
}

// ---------- 256x256 GEMM, merged 4-phase, single barrier, SPLIT lgkm wait ----------
// SESSION-BEST (r14): bf16 MFMA, 8 waves 2x4, 128 KiB LDS, band raster.
// Reads ordered a0,b,a1 (SB0-pinned; DS returns in-order per wave);
// lgkmcnt(4) -> a0+b done -> 16 MFMA (mh0); lgkmcnt(0) -> a1 -> 16 MFMA (mh1).
// LDS [slot][op][kh][256x32] bf16, 64 B rows, swizzle c ^= (row&6)<<3 (both sides).
// Stage map (iter u, t1=2u+1, n0=2u+2, n1=2u+3), 2 units/phase, vmcnt(8)/phase:
//   MP1(s0,kh0): {Ak1,Bk1}(t1)->s1   MP2(s0,kh1): {Ak0,Bk0}(n0)->s0
//   MP3(s1,kh0): {Ak1,Bk1}(n0)->s0   MP4(s1,kh1): {Ak0,Bk0}(n1)->s1
// Ledger: stage targets freed at prior end-barrier; each wave passes its counted
// vmcnt BEFORE the end barrier -> staged group visible at release.
// Measured plateau: GEMM ~680 µs ≈ 52% of bf16 µbench ceiling; phase = MFMA(1242)
// + LDS(~1000) + sync, serial — 9 schedule variants and 4 structural variants
// (r7-r19) all null or worse. Traffic levers (raster, bf16) were the real wins.

__device__ __forceinline__ void rd4(short8 (&d)[4], const char* base) {
#pragma unroll
  for (int i = 0; i < 4; ++i) d[i] = *(const short8*)(base + i * 1024);
}

__device__ __forceinline__ void mfma16(f32x4 (&acc)[8][4], const short8 (&a)[4],
                                       const short8 (&b)[4], int mh) {
#pragma unroll
  for (int i = 0; i < 4; ++i)
#pragma unroll
    for (int j = 0; j < 4; ++j)
      acc[mh * 4 + i][j] =
          __builtin_amdgcn_mfma_f32_16x16x32_bf16(a[i], b[j], acc[mh * 4 + i][j], 0, 0, 0);
}

#define BAR() __builtin_amdgcn_s_barrier()
#define SB0() __builtin_amdgcn_sched_barrier(0)
#define PRIO1() __builtin_amdgcn_s_setprio(1)
#define PRIO0() __builtin_amdgcn_s_setprio(0)
#define VMCNT(N) asm volatile("s_waitcnt vmcnt(" #N ")" ::: "memory")
#define LGKM(N) asm volatile("s_waitcnt lgkmcnt(" #N ")" ::: "memory")

#define STAGE(OP, KH, KT, S)                                                          \
  do {                                                                                \
    const half_t* g_ = ((OP) ? pBsrc : pAsrc) + (KT) * 64 + (KH) * 32;                \
    char* d_ = (char*)&lds[S][OP][KH][0] + wvoff;                                     \
    __builtin_amdgcn_global_load_lds((gvoid_t*)g_, (lvoid_t*)d_, 16, 0, 0);           \
    __builtin_amdgcn_global_load_lds((gvoid_t*)(g_ + 128 * IN_F),                     \
                                     (lvoid_t*)(d_ + 8192), 16, 0, 0);                \
  } while (0)

// Merged phase, ONE barrier, split lgkm. FENCE: 8 = vmcnt(8), -1 = none
#define MPH(SL, KH, S1OP, S1KT, S1SL, S1KH, S2OP, S2KT, S2SL, S2KH, FENCE)   \
  do {                                                                       \
    rd4(a0, (const char*)&lds[SL][0][KH][0] + aoff);                         \
    rd4(b, (const char*)&lds[SL][1][KH][0] + boff);                          \
    SB0();  /* pin: a0+b issue before a1 (in-order DS returns) */            \
    rd4(a1, (const char*)&lds[SL][0][KH][0] + aoff + 4096);                  \
    STAGE(S1OP, S1KH, S1KT, S1SL);                                           \
    STAGE(S2OP, S2KH, S2KT, S2SL);                                           \
    LGKM(4); SB0(); PRIO1();  /* a0 + b landed */                            \
    mfma16(acc, a0, b, 0);                                                   \
    LGKM(0); SB0();           /* a1 landed */                                \
    mfma16(acc, a1, b, 1);                                                   \
    PRIO0();                                                                 \
    if ((FENCE) == 8) VMCNT(8);                                              \
    BAR(); SB0();                                                            \
  } while (0)

// Merged phase, no stages (peeled tail). FENCE: 8/4/0/-1
#define MPHN(SL, KH, FENCE)                                                  \
  do {                                                                       \
    rd4(a0, (const char*)&lds[SL][0][KH][0] + aoff);                         \
    rd4(b, (const char*)&lds[SL][1][KH][0] + boff);                          \
    SB0();                                                                   \
    rd4(a1, (const char*)&lds[SL][0][KH][0] + aoff + 4096);                  \
    LGKM(4); SB0(); PRIO1();                                                 \
    mfma16(acc, a0, b, 0);                                                   \
    LGKM(0); SB0();                                                          \
    mfma16(acc, a1, b, 1);                                                   \
    PRIO0();                                                                 \
    if ((FENCE) == 4) VMCNT(4);                                              \
    if ((FENCE) == 0) VMCNT(0);                                              \
    BAR(); SB0();                                                            \
  } while (0)

__global__ __launch_bounds__(512, 1) void gemm_k(const half_t* __restrict__ A,
                                                 const half_t* __restrict__ B,
                                                 const float* __restrict__ bias,
                                                 float* __restrict__ C) {
  __shared__ __align__(16) half_t lds[2][2][2][8192];  // 128 KiB

  const int tid = threadIdx.x;
  const int lane = tid & 63;
  const int wv = tid >> 6;
  const int wm = wv >> 2;      // 2 wave-rows (128 rows)
  const int wn = wv & 3;       // 4 wave-cols (64 cols)
  const int wvoff = wv << 10;

  // Band-rasterized, XCD-aware map (nwg = 1376 = 8*172, bijective):
  const int nwg = gridDim.x;
  const int perx = nwg >> 3;  // 172
  const int L = ((int)blockIdx.x & 7) * perx + ((int)blockIdx.x >> 3);
  const int band = L >> 7;
  const int rr_ = L & 127;
  const int bn0 = band << 2;
  const int cols = (43 - bn0) < 4 ? (43 - bn0) : 4;
  const int bm = rr_ / cols;
  const int bn = bn0 + rr_ % cols;
  const int row0 = bm * BM;
  const int col0 = bn * BN;

  // staging source (pre-swizzled; involution c ^= (row&6)<<3)
  const int c16 = (tid & 3) * 16;
  const int srow = tid >> 2;
  const int clog = c16 ^ ((srow & 6) << 3);
  const int kidx = clog >> 1;
  const half_t* pAsrc = A + (size_t)(row0 + srow) * IN_F + kidx;
  const half_t* pBsrc = B + (size_t)(col0 + srow) * IN_F + kidx;

  // fragment read offsets (swizzled); frag stride 16 rows * 64 B = 1024
  const int r16 = lane & 15;
  const int kg = lane >> 4;
  const int arow = wm * 128 + r16;
  const int brow = wn * 64 + r16;
  const int aoff = arow * 64 + ((kg * 16) ^ ((arow & 6) << 3));
  const int boff = brow * 64 + ((kg * 16) ^ ((brow & 6) << 3));

  f32x4 acc[8][4];
#pragma unroll
  for (int m = 0; m < 8; ++m)
#pragma unroll
    for (int n = 0; n < 4; ++n) acc[m][n] = (f32x4){0.f, 0.f, 0.f, 0.f};

  // prologue: tile0 all 4 units + tile1 {Ak0,Bk0}. vmcnt(4): tile0 landed.
  STAGE(0, 0, 0, 0);
  STAGE(1, 0, 0, 0);
  STAGE(0, 1, 0, 0);
  STAGE(1, 1, 0, 0);
  STAGE(0, 0, 1, 1);
  STAGE(1, 0, 1, 1);
  VMCNT(4);
  BAR();
  SB0();

  short8 a0[4], a1[4], b[4];
  for (int u = 0; u < 31; ++u) {
    const int t1 = 2 * u + 1, n0 = 2 * u + 2, n1 = 2 * u + 3;
    MPH(0, 0, 0, t1, 1, 1, 1, t1, 1, 1, 8);  // MP1: s0kh0; stage {Ak1,Bk1}(t1)->s1
    MPH(0, 1, 0, n0, 0, 0, 1, n0, 0, 0, 8);  // MP2: s0kh1; stage {Ak0,Bk0}(n0)->s0
    MPH(1, 0, 0, n0, 0, 1, 1, n0, 0, 1, 8);  // MP3: s1kh0; stage {Ak1,Bk1}(n0)->s0
    MPH(1, 1, 0, n1, 1, 0, 1, n1, 1, 0, 8);  // MP4: s1kh1; stage {Ak0,Bk0}(n1)->s1
  }
  {  // peeled iter 31 (t0=62, t1=63): MP1 stages {Ak1,Bk1}(63); drain 8/4/0
    MPH(0, 0, 0, 63, 1, 1, 1, 63, 1, 1, 8);
    MPHN(0, 1, 4);
    MPHN(1, 0, 0);
    MPHN(1, 1, -1);
  }

  // epilogue: fp16 rounding + fp16 bias add (reference numerics), NT fp32 store
  const int kg4 = kg * 4;
#pragma unroll
  for (int nf = 0; nf < 4; ++nf) {
    int col = col0 + wn * 64 + nf * 16 + r16;
    _Float16 bh = (_Float16)bias[col];
#pragma unroll
    for (int mf = 0; mf < 8; ++mf) {
      int rb = row0 + wm * 128 + mf * 16 + kg4;
#pragma unroll
      for (int r = 0; r < 4; ++r) {
        _Float16 v = (_Float16)acc[mf][nf][r] + bh;
        __builtin_nontemporal_store((float)v, &C[(size_t)(rb + r) * OUT_F + col]);
      }
    }
  }
}

// ---------------- emergency fallback (ws too small) ----------------
__global__ void naive_k(const float* __restrict__ x, const int* __restrict__ wq,
                        const float* __restrict__ scales, const float* __restrict__ bias,
                        float* __restrict__ out) {
  long idx = (long)blockIdx.x * blockDim.x + threadIdx.x;
  if (idx >= (long)M_TOTAL * OUT_F) return;
  int m = (int)(idx / OUT_F);
  int n = (int)(idx % OUT_F);
  float acc = 0.f;
  for (int g = 0; g < NGROUPS; ++g) {
    float s = scales[n * NGROUPS + g];
    for (int k = g * 128; k < (g + 1) * 128; ++k) {
      _Float16 xv = (_Float16)x[(size_t)m * IN_F + k];
      _Float16 wv = (_Float16)((float)wq[(size_t)n * IN_F + k] * s);
      acc += (float)xv * (float)wv;
    }
  }
  _Float16 r = (_Float16)acc + (_Float16)bias[n];
  out[idx] = (float)r;
}

extern "C" void kernel_launch(void* const* d_in, const int* in_sizes, int n_in,
                              void* d_out, int out_size, void* d_ws, size_t ws_size,
                              hipStream_t stream) {
  const float* x = (const float*)d_in[0];
  const int* wq = (const int*)d_in[1];
  const float* scales = (const float*)d_in[2];
  const float* bias = (const float*)d_in[3];
  float* out = (float*)d_out;

  const size_t xh_bytes = (size_t)M_TOTAL * IN_F * 2;
  const size_t wh_bytes = (size_t)OUT_F * IN_F * 2;

  if (ws_size >= xh_bytes + wh_bytes) {
    ushort_t* xh = (ushort_t*)d_ws;
    ushort_t* wh = (ushort_t*)((char*)d_ws + xh_bytes);
    convert_x_k<<<2048, 256, 0, stream>>>(x, xh);
    dequant_w_k<<<OUT_F, 512, 0, stream>>>(wq, scales, wh);
    gemm_k<<<(M_TOTAL / BM) * (OUT_F / BN), 512, 0, stream>>>(
        (const half_t*)xh, (const half_t*)wh, bias, out);
  } else {
    long total = (long)M_TOTAL * OUT_F;
    naive_k<<<(int)((total + 255) / 256), 256, 0, stream>>>(x, wq, scales, bias, out);
  }
}